// Round 8
// baseline (478.043 us; speedup 1.0000x reference)
//
#include <hip/hip_runtime.h>
#include <hip/hip_bf16.h>

#define CIN   128
#define EMBD  64
#define KC    512
#define SPAT  32768
#define NVOX  131072
#define QSZ   (NVOX * EMBD)      // 8388608
#define DIFF_OFF QSZ
#define IDX_OFF  (QSZ + 1)
#define NBLK  (NVOX / 64)        // 2048 blocks, 64 voxels each

typedef __attribute__((ext_vector_type(8))) short bf16x8;
typedef __attribute__((ext_vector_type(4))) float f32x4;

__device__ __forceinline__ short bf_hi(float f) {
  __hip_bfloat16 h = __float2bfloat16(f);
  return *(short*)&h;
}
__device__ __forceinline__ float bf_f(short s) {
  __hip_bfloat16 h = *(__hip_bfloat16*)&s;
  return __bfloat162float(h);
}

// ---------------------------------------------------------------------------
// Prep E: embedT[k][o] f32 rows, norms, 3-way bf16 split e_h/e_m/e_l
// ---------------------------------------------------------------------------
__global__ __launch_bounds__(64) void vq_prep_e(const float* __restrict__ embed,
                                                float* __restrict__ embedT,
                                                float* __restrict__ norms,
                                                short* __restrict__ e_h,
                                                short* __restrict__ e_m,
                                                short* __restrict__ e_l) {
  int k = blockIdx.x;   // code
  int o = threadIdx.x;  // emb
  float e = embed[o * KC + k];
  embedT[k * EMBD + o] = e;
  short h = bf_hi(e);
  float r1 = e - bf_f(h);
  short m = bf_hi(r1);
  e_h[k * EMBD + o] = h;
  e_m[k * EMBD + o] = m;
  e_l[k * EMBD + o] = bf_hi(r1 - bf_f(m));
  float s = e * e;
  #pragma unroll
  for (int off = 32; off > 0; off >>= 1) s += __shfl_down(s, off);
  if (o == 0) norms[k] = s;
}

__global__ __launch_bounds__(256) void vq_prep_w(const float* __restrict__ conv_w,
                                                 float* __restrict__ wT) {
  int f = blockIdx.x * 256 + threadIdx.x;   // 8192
  int c = f >> 6;
  int o = f & 63;
  wT[f] = conv_w[o * CIN + c];
}

// One bf16 MFMA pass over one (z-split, e-split) pair for the current code
// chunk. NO lambda/function: macro -> straight-line, acc stays in registers.
#define DIST_PASS(ZB, EB)                                                     \
  {                                                                           \
    _Pragma("unroll")                                                         \
    for (int ks8 = 0; ks8 <= 4; ks8 += 4) {                                   \
      bf16x8 a[4];                                                            \
      _Pragma("unroll")                                                       \
      for (int m = 0; m < 4; ++m) {                                           \
        int vox = m * 16 + l15;                                               \
        a[m] = *(const bf16x8*)((const char*)(ZB) + vox * 128 +               \
                                (((ks8 + g) ^ (vox & 7)) << 4));              \
      }                                                                       \
      _Pragma("unroll")                                                       \
      for (int n = 0; n < 4; ++n) {                                           \
        bf16x8 bb = *(const bf16x8*)((const char*)(EB) + boff_c +             \
                                     n * 2048 + ks8 * 16);                    \
        _Pragma("unroll")                                                     \
        for (int m = 0; m < 4; ++m)                                           \
          acc[m][n] = __builtin_amdgcn_mfma_f32_16x16x32_bf16(a[m], bb,       \
                                                              acc[m][n],      \
                                                              0, 0, 0);       \
      }                                                                       \
    }                                                                         \
  }

// ---------------------------------------------------------------------------
// Main: 64 voxels/block, 4 waves. Phase 1: exact f32 conv (wave = o-quarter),
// 3-split z into XOR-swizzled LDS. Phase 2: wave = code-quarter; 2 chunks of
// 64 codes, acc[4][4], 6 split passes, fused argmin -> LDS. Epilogue: merge,
// idx, diff = best + ||z||^2, gather quantize from f32 codebook.
// ---------------------------------------------------------------------------
__global__ __launch_bounds__(256, 4) void vq_main(
    const float* __restrict__ x, const float* __restrict__ wT,
    const float* __restrict__ conv_b, const float* __restrict__ embedT,
    const short* __restrict__ e_h, const short* __restrict__ e_m,
    const short* __restrict__ e_l, const float* __restrict__ norms,
    float* __restrict__ out, float* __restrict__ partials) {
  __shared__ short zh[64 * 64], zm[64 * 64], zl[64 * 64];  // 8KB each, swizzled
  __shared__ float norml[KC];
  __shared__ float zsq4[64][4];
  __shared__ float wbest_s[4][2][64];
  __shared__ int   widx_s[4][2][64];
  __shared__ int   fidx[64];

  const int t   = threadIdx.x;
  const int q   = t >> 6;        // wave id
  const int v   = t & 63;        // voxel (phase 1)
  const int n0  = blockIdx.x * 64;
  const int b   = n0 >> 15;
  const int vsp = n0 & (SPAT - 1);

  norml[t]       = norms[t];
  norml[t + 256] = norms[t + 256];

  // ---- Phase 1: conv, wave q owns o-range [q*16, q*16+16) ----
  const float* xp = x + ((size_t)b * CIN) * SPAT + vsp + v;
  float z[16];
  #pragma unroll
  for (int j = 0; j < 16; ++j) z[j] = conv_b[q * 16 + j];

  #pragma unroll 4
  for (int c = 0; c < CIN; ++c) {
    float xv = xp[(size_t)c * SPAT];           // 256B coalesced per wave
    const float* wr = wT + c * EMBD + q * 16;  // wave-uniform -> s_load
    #pragma unroll
    for (int j = 0; j < 16; ++j) z[j] = fmaf(xv, wr[j], z[j]);
  }

  float sq = 0.f;
  #pragma unroll
  for (int j = 0; j < 16; ++j) sq = fmaf(z[j], z[j], sq);
  zsq4[v][q] = sq;

  // 3-way split -> swizzled LDS: [vox][64] bf16, 16B-subblock s ^= (vox&7)
  short h16[16], m16[16], l16[16];
  #pragma unroll
  for (int j = 0; j < 16; ++j) {
    short h = bf_hi(z[j]);
    float r1 = z[j] - bf_f(h);
    short m = bf_hi(r1);
    h16[j] = h; m16[j] = m; l16[j] = bf_hi(r1 - bf_f(m));
  }
  #pragma unroll
  for (int jj = 0; jj < 2; ++jj) {
    int s = (2 * q + jj) ^ (v & 7);
    int byte = v * 128 + s * 16;
    bf16x8 hv, mv, lv;
    #pragma unroll
    for (int j = 0; j < 8; ++j) {
      hv[j] = h16[jj * 8 + j]; mv[j] = m16[jj * 8 + j]; lv[j] = l16[jj * 8 + j];
    }
    *(bf16x8*)((char*)zh + byte) = hv;
    *(bf16x8*)((char*)zm + byte) = mv;
    *(bf16x8*)((char*)zl + byte) = lv;
  }
  __syncthreads();

  // ---- Phase 2: wave q owns codes [q*128, q*128+128), 2 chunks of 64 ----
  const int lane = t & 63;
  const int l15  = lane & 15;
  const int g    = lane >> 4;

  #pragma unroll
  for (int nc = 0; nc < 2; ++nc) {
    const int boff_c = (q * 128 + nc * 64 + l15) * 128 + g * 16;

    f32x4 acc[4][4];
    #pragma unroll
    for (int m = 0; m < 4; ++m)
      #pragma unroll
      for (int n = 0; n < 4; ++n) { f32x4 z4 = {0.f, 0.f, 0.f, 0.f}; acc[m][n] = z4; }

    DIST_PASS(zh, e_h)   // hh
    DIST_PASS(zh, e_m)   // hm
    DIST_PASS(zm, e_h)   // mh
    DIST_PASS(zh, e_l)   // hl
    DIST_PASS(zl, e_h)   // lh
    DIST_PASS(zm, e_m)   // mm   (dropped terms ~2^-27 relative)

    // scores = norms - 2*dot; per-(m,r) argmin over n (codes ascending)
    float best[16]; int bidx[16];
    #pragma unroll
    for (int i = 0; i < 16; ++i) { best[i] = 3.4e38f; bidx[i] = 0; }
    #pragma unroll
    for (int n = 0; n < 4; ++n) {
      float nv = norml[q * 128 + nc * 64 + n * 16 + l15];
      int code = q * 128 + nc * 64 + n * 16 + l15;
      #pragma unroll
      for (int m = 0; m < 4; ++m)
        #pragma unroll
        for (int r = 0; r < 4; ++r) {
          float s = fmaf(-2.f, acc[m][n][r], nv);
          int i = m * 4 + r;
          bool tk = s < best[i];             // ascending n -> first min kept
          best[i] = tk ? s : best[i];
          bidx[i] = tk ? code : bidx[i];
        }
    }
    // reduce over the 16 lanes of the l15 group (tie -> smaller code)
    #pragma unroll
    for (int i = 0; i < 16; ++i) {
      #pragma unroll
      for (int d = 1; d < 16; d <<= 1) {
        float os = __shfl_xor(best[i], d);
        int   oi = __shfl_xor(bidx[i], d);
        bool tk = (os < best[i]) || (os == best[i] && oi < bidx[i]);
        best[i] = tk ? os : best[i];
        bidx[i] = tk ? oi : bidx[i];
      }
    }
    if (l15 == 0) {
      #pragma unroll
      for (int i = 0; i < 16; ++i) {
        int vox = (i >> 2) * 16 + g * 4 + (i & 3);
        wbest_s[q][nc][vox] = best[i];
        widx_s[q][nc][vox]  = bidx[i];
      }
    }
  }
  __syncthreads();

  // ---- merge 8 candidates (code ranges ascending in (q,nc)) ----
  if (t < 64) {
    float bs = wbest_s[0][0][t]; int bi = widx_s[0][0][t];
    #pragma unroll
    for (int qq = 0; qq < 4; ++qq)
      #pragma unroll
      for (int nc = 0; nc < 2; ++nc) {
        if (qq == 0 && nc == 0) continue;
        float s2 = wbest_s[qq][nc][t];
        int   i2 = widx_s[qq][nc][t];
        bool tk = s2 < bs;                   // strict < -> smallest code wins
        bs = tk ? s2 : bs; bi = tk ? i2 : bi;
      }
    fidx[t] = bi;
    out[IDX_OFF + n0 + t] = (float)bi;
    float d = bs + zsq4[t][0] + zsq4[t][1] + zsq4[t][2] + zsq4[t][3];
    #pragma unroll
    for (int off = 32; off > 0; off >>= 1) d += __shfl_down(d, off);
    if (t == 0) partials[blockIdx.x] = d;
  }
  __syncthreads();

  // ---- quantize: thread t -> voxel v, o-quarter q; exact f32 gather ----
  const int bi = fidx[v];
  const float* er = embedT + bi * EMBD + q * 16;
  float* qout = out + ((size_t)b * EMBD + q * 16) * SPAT + vsp + v;
  #pragma unroll
  for (int u = 0; u < 4; ++u) {
    float4 e4 = *(const float4*)(er + u * 4);
    qout[(size_t)(u * 4 + 0) * SPAT] = e4.x;
    qout[(size_t)(u * 4 + 1) * SPAT] = e4.y;
    qout[(size_t)(u * 4 + 2) * SPAT] = e4.z;
    qout[(size_t)(u * 4 + 3) * SPAT] = e4.w;
  }
}

__global__ __launch_bounds__(512) void vq_final(const float* __restrict__ partials,
                                                float* __restrict__ out) {
  __shared__ float tmp[8];
  float s = partials[threadIdx.x] + partials[threadIdx.x + 512] +
            partials[threadIdx.x + 1024] + partials[threadIdx.x + 1536];
  #pragma unroll
  for (int off = 32; off > 0; off >>= 1) s += __shfl_down(s, off);
  if ((threadIdx.x & 63) == 0) tmp[threadIdx.x >> 6] = s;
  __syncthreads();
  if (threadIdx.x == 0) {
    float t = 0.f;
    #pragma unroll
    for (int i = 0; i < 8; ++i) t += tmp[i];
    out[DIFF_OFF] = t * (1.0f / (float)QSZ);
  }
}

extern "C" void kernel_launch(void* const* d_in, const int* in_sizes, int n_in,
                              void* d_out, int out_size, void* d_ws, size_t ws_size,
                              hipStream_t stream) {
  const float* x      = (const float*)d_in[0];
  const float* conv_w = (const float*)d_in[1];
  const float* conv_b = (const float*)d_in[2];
  const float* embed  = (const float*)d_in[3];
  float* out = (float*)d_out;
  float* ws  = (float*)d_ws;

  float* embedT   = ws;              // 32768 f32
  float* norms    = ws + 32768;      // 512
  float* wT       = ws + 33280;      // 8192
  float* partials = ws + 41472;      // 2048
  short* e_h      = (short*)(ws + 43520);   // 32768 bf16 each
  short* e_m      = e_h + KC * EMBD;
  short* e_l      = e_m + KC * EMBD;

  vq_prep_e<<<KC, EMBD, 0, stream>>>(embed, embedT, norms, e_h, e_m, e_l);
  vq_prep_w<<<32, 256, 0, stream>>>(conv_w, wT);
  vq_main<<<NBLK, 256, 0, stream>>>(x, wT, conv_b, embedT, e_h, e_m, e_l,
                                    norms, out, partials);
  vq_final<<<1, 512, 0, stream>>>(partials, out);
}